// Round 2
// baseline (150.698 us; speedup 1.0000x reference)
//
#include <hip/hip_runtime.h>
#include <math.h>

#define KNBR 16
#define DIM 64
#define NREL 32

#define Q8SCALE 512.0f          // |x| <= 127/512 = 0.248 = 5 sigma; step 1/512
#define Q4SCALE 28.0f           // |x| <= 7/28 = 0.25 = 5 sigma; step 1/28

__device__ __forceinline__ int irl(int v, int l) {
    return __builtin_amdgcn_readlane(v, l);
}
__device__ __forceinline__ float frl(float v, int l) {
    return __int_as_float(__builtin_amdgcn_readlane(__float_as_int(v), l));
}

// ---- Pre-pass: build quantized tables in ws.
//  d8  : entity_emb int8  (x*512), 6.4MB  -- hop-1/self rows (accuracy-critical)
//  d4  : entity_emb int4  (x*28), 3.2MB  -- hop-2 rows; fits a 4MB per-XCD L2
//  r8  : adj_relation int8 (exact, values<32), 1.6MB -- L2-resident
__global__ void convert_tabs(const float* __restrict__ emb,
                             const int* __restrict__ adj_rel,
                             signed char* __restrict__ d8,
                             unsigned char* __restrict__ d4,
                             unsigned char* __restrict__ r8,
                             int n4, int nrel4)
{
    const int stride = gridDim.x * blockDim.x;
    for (int i = blockIdx.x * blockDim.x + threadIdx.x; i < n4; i += stride) {
        float4 f = ((const float4*)emb)[i];
        // int8 table
        int q0 = (int)rintf(fminf(fmaxf(f.x * Q8SCALE, -127.f), 127.f));
        int q1 = (int)rintf(fminf(fmaxf(f.y * Q8SCALE, -127.f), 127.f));
        int q2 = (int)rintf(fminf(fmaxf(f.z * Q8SCALE, -127.f), 127.f));
        int q3 = (int)rintf(fminf(fmaxf(f.w * Q8SCALE, -127.f), 127.f));
        ((char4*)d8)[i] = make_char4((signed char)q0, (signed char)q1,
                                     (signed char)q2, (signed char)q3);
        // int4 table: 2 dims/byte, low nibble = even dim
        int p0 = (int)rintf(fminf(fmaxf(f.x * Q4SCALE, -7.f), 7.f));
        int p1 = (int)rintf(fminf(fmaxf(f.y * Q4SCALE, -7.f), 7.f));
        int p2 = (int)rintf(fminf(fmaxf(f.z * Q4SCALE, -7.f), 7.f));
        int p3 = (int)rintf(fminf(fmaxf(f.w * Q4SCALE, -7.f), 7.f));
        unsigned char b0 = (unsigned char)((p0 & 0xF) | ((p1 & 0xF) << 4));
        unsigned char b1 = (unsigned char)((p2 & 0xF) | ((p3 & 0xF) << 4));
        ((uchar2*)d4)[i] = make_uchar2(b0, b1);
        // relation int8 (exact)
        if (i < nrel4) {
            int4 r = ((const int4*)adj_rel)[i];
            ((uchar4*)r8)[i] = make_uchar4((unsigned char)r.x, (unsigned char)r.y,
                                           (unsigned char)r.z, (unsigned char)r.w);
        }
    }
}

// R15: latency-bound gather kernel; time ~ line_requests x avg_latency (per-CU
// miss concurrency is pinned -- R14 evidence: -14% lines -> -11% time).
// Changes vs R14:
//  (a) hop-2 gathers hit a 3.2MB int4 table -> fully L2-resident per XCD,
//      ~500-900cy mixed latency -> ~200cy L2-hit on 83% of the request stream.
//  (b) adj_relation reads from a 1.6MB exact int8 copy (L2-resident).
//  Accuracy: int4 err is double-damped (attn-mean x 1/16, then x 1/16 at L1
//  agg) -> ~1e-5 at output; hop-1/self stay int8.
template <bool Q8>
__global__ __launch_bounds__(64, 4) void kgnnls_kernel(
    const int* __restrict__ u_ids, const int* __restrict__ i_ids,
    const int* __restrict__ adj_entity, const int* __restrict__ adj_relation,
    const float* __restrict__ user_emb, const float* __restrict__ entity_emb,
    const signed char* __restrict__ et8,
    const unsigned char* __restrict__ et4,
    const unsigned char* __restrict__ rel8,
    const float* __restrict__ relation_emb,
    const float* __restrict__ W0, const float* __restrict__ b0,
    const float* __restrict__ W1, const float* __restrict__ b1,
    float* __restrict__ out, int B)
{
    const int lane = threadIdx.x;       // dual role: dim index d / output index e
    const int b = blockIdx.x;           // grid == B exactly

    __shared__ float xbuf[17][DIM];
    __shared__ float uebuf[DIM];

    const int u  = u_ids[b];
    const int i0 = i_ids[b];

    const float ue = user_emb[u * DIM + lane];
    uebuf[lane] = ue;
    const float bias0 = b0[lane];
    __syncthreads();

    // s[r] at lane r (r < 33): s = (1/64) * dot(ue, relation_emb[r])
    float s_val = 0.f;
    if (lane < NREL + 1) {
        const float4* rrow = (const float4*)(relation_emb + lane * DIM);
        const float4* ub   = (const float4*)uebuf;
        float acc = 0.f;
        #pragma unroll
        for (int q = 0; q < 16; ++q) {
            float4 r4 = rrow[q];
            float4 u4 = ub[q];   // same address across lanes -> LDS broadcast
            acc += r4.x*u4.x + r4.y*u4.y + r4.z*u4.z + r4.w*u4.w;
        }
        s_val = acc * (1.0f / DIM);
    }

    // hop-0 neighbor/relation indices at lanes 0..15
    int e1k = 0, r0k = 0;
    if (lane < KNBR) {
        e1k = adj_entity[i0 * KNBR + lane];
        r0k = Q8 ? (int)rel8[i0 * KNBR + lane]
                 : adj_relation[i0 * KNBR + lane];
    }

    // softmax over k (16) for hop-0 scores, valid at lanes 0..15
    float sc0 = __shfl(s_val, r0k);      // data-dependent lane -> bpermute
    float m0 = sc0;
    m0 = fmaxf(m0, __shfl_xor(m0, 1));
    m0 = fmaxf(m0, __shfl_xor(m0, 2));
    m0 = fmaxf(m0, __shfl_xor(m0, 4));
    m0 = fmaxf(m0, __shfl_xor(m0, 8));
    float ex0 = __expf(sc0 - m0);
    float z0 = ex0;
    z0 += __shfl_xor(z0, 1);
    z0 += __shfl_xor(z0, 2);
    z0 += __shfl_xor(z0, 4);
    z0 += __shfl_xor(z0, 8);
    const float attn0 = ex0 / z0;     // lanes 0..15 hold attn0[k]

    // hop-1: lane handles k = lane>>2, j in [4*(lane&3), +4)
    const int kk = lane >> 2;
    const int jb = (lane & 3) * 4;
    const int ek = __shfl(e1k, kk);   // per-lane index -> bpermute
    const int4 e2i = *(const int4*)(adj_entity + ek * KNBR + jb);
    int e2idx[4] = { e2i.x, e2i.y, e2i.z, e2i.w };

    int r2x, r2y, r2z, r2w;
    if (Q8) {
        uchar4 rr = *(const uchar4*)(rel8 + ek * KNBR + jb);  // 4B-aligned
        r2x = rr.x; r2y = rr.y; r2z = rr.z; r2w = rr.w;
    } else {
        const int4 r2i = *(const int4*)(adj_relation + ek * KNBR + jb);
        r2x = r2i.x; r2y = r2i.y; r2z = r2i.z; r2w = r2i.w;
    }

    float sc1[4];
    sc1[0] = __shfl(s_val, r2x);      // data-dependent lanes -> bpermute
    sc1[1] = __shfl(s_val, r2y);
    sc1[2] = __shfl(s_val, r2z);
    sc1[3] = __shfl(s_val, r2w);

    // softmax over the 16 j's: intra-lane over 4 + xor over lanes {1,2}
    float m1 = fmaxf(fmaxf(sc1[0], sc1[1]), fmaxf(sc1[2], sc1[3]));
    m1 = fmaxf(m1, __shfl_xor(m1, 1));
    m1 = fmaxf(m1, __shfl_xor(m1, 2));
    float a1[4];
    float z1 = 0.f;
    #pragma unroll
    for (int t = 0; t < 4; ++t) { a1[t] = __expf(sc1[t] - m1); z1 += a1[t]; }
    z1 += __shfl_xor(z1, 1);
    z1 += __shfl_xor(z1, 2);
    const float inv_z1 = 1.0f / z1;
    #pragma unroll
    for (int t = 0; t < 4; ++t) a1[t] *= inv_z1;

    // ---- Gather phase ----
    // hop-1/self rows from the int8 table (raw loads, cvt deferred).
    int v1raw[KNBR];
    #pragma unroll
    for (int k = 0; k < KNBR; ++k) {
        const int ei = irl(e1k, k);                    // imm lane -> SGPR
        v1raw[k] = Q8 ? (int)et8[(size_t)ei * DIM + lane]
                      : __float_as_int(entity_emb[(size_t)ei * DIM + lane]);
    }
    const int ev0raw = Q8 ? (int)et8[(size_t)i0 * DIM + lane]
                          : __float_as_int(entity_emb[(size_t)i0 * DIM + lane]);

    // hop-2: int4 table, row = 32B; lane d reads byte idx*32 + (d>>1),
    // then extracts its nibble at consume time (issue slots stay pure loads).
    const int sh = 28 - ((lane & 1) << 2);   // even lane: <<28; odd: <<24
    auto issue = [&](int* v2, int k) {
        #pragma unroll
        for (int j = 0; j < 16; ++j) {
            const int src = 4 * k + (j >> 2);          // static after unroll
            const int ei2 = irl(e2idx[j & 3], src);
            v2[j] = Q8 ? (int)et4[(size_t)ei2 * 32 + (lane >> 1)]
                       : __float_as_int(entity_emb[(size_t)ei2 * DIM + lane]);
        }
    };
    auto consume = [&](const int* v2, int k) -> float {
        float acc = 0.f;
        #pragma unroll
        for (int j = 0; j < 16; ++j) {
            const float w = frl(a1[j & 3], 4 * k + (j >> 2));  // SGPR operand
            float v;
            if (Q8) {
                const int t = ((int)((unsigned)v2[j] << sh)) >> 28;  // nibble
                v = (float)t;
            } else {
                v = __int_as_float(v2[j]);
            }
            acc += w * v;
        }
        return acc;
    };
    const float xsc = Q8 ? (1.0f / (KNBR * Q4SCALE)) : (1.0f / KNBR);
    const float vsc = Q8 ? (1.0f / Q8SCALE) : 1.0f;

    float agg0 = 0.f;
    int v2a[16], v2b[16];
    issue(v2a, 0);
    #pragma unroll
    for (int k = 0; k < KNBR; k += 2) {
        issue(v2b, k + 1);                    // keep ~32 lines in flight
        const float acca = consume(v2a, k);
        if (k + 2 < KNBR) issue(v2a, k + 2);  // compile-time after unroll
        const float accb = consume(v2b, k + 1);
        const float v1k0 = (Q8 ? (float)v1raw[k]     : __int_as_float(v1raw[k]))     * vsc;
        const float v1k1 = (Q8 ? (float)v1raw[k + 1] : __int_as_float(v1raw[k + 1])) * vsc;
        agg0 += frl(attn0, k) * v1k0 + frl(attn0, k + 1) * v1k1;
        xbuf[1 + k][lane] = v1k0 + acca * xsc;
        xbuf[2 + k][lane] = v1k1 + accb * xsc;
    }
    const float ev0 = (Q8 ? (float)ev0raw : __int_as_float(ev0raw)) * vsc;
    xbuf[0][lane] = ev0 + agg0 * (1.0f / KNBR);
    __syncthreads();

    // Layer-0 matmul: h[r][e] = relu( sum_d x[r][d] * W0[e][d] + b0[e] ), 17 rows
    float h[17];
    {
        #pragma unroll
        for (int r = 0; r < 17; ++r) h[r] = bias0;
        const float4* wrow = (const float4*)(W0 + lane * DIM);
        #pragma unroll
        for (int q = 0; q < 16; ++q) {
            float4 w = wrow[q];   // L1-resident
            #pragma unroll
            for (int r = 0; r < 17; ++r) {
                float4 xv = ((const float4*)xbuf[r])[q];  // broadcast read
                h[r] += xv.x * w.x + xv.y * w.y + xv.z * w.z + xv.w * w.w;
            }
        }
        #pragma unroll
        for (int r = 0; r < 17; ++r) h[r] = fmaxf(h[r], 0.f);
    }

    // Layer-1: agg over h1 with the SAME attn0, then tanh((h0+agg) @ W1^T + b1)
    float aggL = 0.f;
    #pragma unroll
    for (int k = 0; k < KNBR; ++k)
        aggL += frl(attn0, k) * h[1 + k];              // imm-lane readlane
    const float xL = h[0] + aggL * (1.0f / KNBR);
    __syncthreads();
    xbuf[0][lane] = xL;
    __syncthreads();

    float acc1 = b1[lane];
    {
        const float4* wrow = (const float4*)(W1 + lane * DIM);
        const float4* xb   = (const float4*)xbuf[0];
        #pragma unroll
        for (int q = 0; q < 16; ++q) {
            float4 w  = wrow[q];
            float4 xv = xb[q];
            acc1 += xv.x * w.x + xv.y * w.y + xv.z * w.z + xv.w * w.w;
        }
    }
    const float item = tanhf(acc1);

    // score = sigmoid( sum_d ue[d] * item[d] )
    float p = ue * item;
    #pragma unroll
    for (int m = 1; m < 64; m <<= 1) p += __shfl_xor(p, m);
    if (lane == 0) out[b] = 1.0f / (1.0f + __expf(-p));
}

extern "C" void kernel_launch(void* const* d_in, const int* in_sizes, int n_in,
                              void* d_out, int out_size, void* d_ws, size_t ws_size,
                              hipStream_t stream) {
    const int*   u_ids        = (const int*)  d_in[0];
    const int*   i_ids        = (const int*)  d_in[1];
    const int*   adj_entity   = (const int*)  d_in[2];
    const int*   adj_relation = (const int*)  d_in[3];
    const float* user_emb     = (const float*)d_in[4];
    const float* entity_emb   = (const float*)d_in[5];
    const float* relation_emb = (const float*)d_in[6];
    const float* W0           = (const float*)d_in[7];
    const float* b0           = (const float*)d_in[8];
    const float* W1           = (const float*)d_in[9];
    const float* b1           = (const float*)d_in[10];
    float* out = (float*)d_out;

    const int B      = in_sizes[0];
    const int n_emb  = in_sizes[5];                 // N_ENTITIES * DIM (6.4M)
    const int n_rel  = in_sizes[3];                 // N_ENTITIES * K   (1.6M)
    // ws layout: [0,n_emb) int8 | [n_emb, n_emb*3/2) int4 | [.., +n_rel) rel8
    const size_t off4   = (size_t)n_emb;
    const size_t offr   = off4 + (size_t)n_emb / 2;
    const size_t ws_needed = offr + (size_t)n_rel;

    if (ws_size >= ws_needed) {
        signed char*   et8  = (signed char*)d_ws;
        unsigned char* et4  = (unsigned char*)d_ws + off4;
        unsigned char* rel8 = (unsigned char*)d_ws + offr;
        hipLaunchKernelGGL(convert_tabs, dim3(1024), dim3(256), 0, stream,
            entity_emb, adj_relation, et8, et4, rel8, n_emb / 4, n_rel / 4);
        hipLaunchKernelGGL((kgnnls_kernel<true>), dim3(B), dim3(64), 0, stream,
            u_ids, i_ids, adj_entity, adj_relation, user_emb, entity_emb,
            et8, et4, rel8, relation_emb, W0, b0, W1, b1, out, B);
    } else {
        hipLaunchKernelGGL((kgnnls_kernel<false>), dim3(B), dim3(64), 0, stream,
            u_ids, i_ids, adj_entity, adj_relation, user_emb, entity_emb,
            (const signed char*)entity_emb /*unused*/,
            (const unsigned char*)entity_emb /*unused*/,
            (const unsigned char*)adj_relation /*unused*/,
            relation_emb, W0, b0, W1, b1, out, B);
    }
}

// Round 4
// 150.284 us; speedup vs baseline: 1.0028x; 1.0028x over previous
//
#include <hip/hip_runtime.h>
#include <math.h>

#define KNBR 16
#define DIM 64
#define NREL 32

#define Q8SCALE 512.0f          // |x| <= 127/512 = 0.248 = 5 sigma; step 1/512
#define Q4SCALE 28.0f           // |x| <= 7/28 = 0.25 = 5 sigma; step 1/28

typedef __attribute__((ext_vector_type(8))) short short8;   // 8 bf16 (4 VGPRs)
typedef __attribute__((ext_vector_type(4))) float floatx4;  // MFMA C/D

__device__ __forceinline__ int irl(int v, int l) {
    return __builtin_amdgcn_readlane(v, l);
}
__device__ __forceinline__ float frl(float v, int l) {
    return __int_as_float(__builtin_amdgcn_readlane(__float_as_int(v), l));
}
__device__ __forceinline__ unsigned short f2bf(float x) {   // RNE f32->bf16
    unsigned u = __float_as_uint(x);
    u += 0x7fffu + ((u >> 16) & 1u);
    return (unsigned short)(u >> 16);
}

// ---- Pre-pass: quantized tables in ws + MFMA-layout probe.
//  d8: entity int8 (hop-1/self) | d4: entity int4 (hop-2) | r8: adj_relation
//  w0b: W0 bf16 | rctab/mapflag: per-(lane,reg) D-position table from probe.
// Probe trick: D[m][n] = (m+1) + 16(n+1); every output register's VALUE
// encodes its true (row,col) -> correct under ANY lane permutation; shared
// k-permutations cancel in A*B; non-shared malform values -> flag=0.
__global__ void convert_tabs(const float* __restrict__ emb,
                             const int* __restrict__ adj_rel,
                             const float* __restrict__ W0,
                             signed char* __restrict__ d8,
                             unsigned char* __restrict__ d4,
                             unsigned char* __restrict__ r8,
                             unsigned short* __restrict__ w0b,
                             int* __restrict__ rctab,
                             int* __restrict__ mapflag,
                             int n4, int nrel4, int nw4)
{
    if (blockIdx.x == 0 && threadIdx.x < 64) {
        const int lane = threadIdx.x;
        const int g = lane >> 4, c15 = lane & 15;
        short8 av, bv;
        #pragma unroll
        for (int j = 0; j < 8; ++j) { av[j] = 0; bv[j] = 0; }
        if (g == 0) {
            av[0] = (short)f2bf((float)(c15 + 1));        // A[m][0] = m+1
            av[1] = (short)f2bf(1.0f);                    // A[m][1] = 1
            bv[0] = (short)f2bf(1.0f);                    // B[0][n] = 1
            bv[1] = (short)f2bf((float)(16 * (c15 + 1))); // B[1][n] = 16(n+1)
        }
        floatx4 pacc = {0.f, 0.f, 0.f, 0.f};
        pacc = __builtin_amdgcn_mfma_f32_16x16x32_bf16(av, bv, pacc, 0, 0, 0);
        int okm = 1, sum = 0, rc[4];
        #pragma unroll
        for (int r = 0; r < 4; ++r) {
            const float vc = fminf(fmaxf(pacc[r], 0.f), 1.0e6f);
            const int iv = (int)vc;
            const int mm = (iv - 17) & 15;
            const int nn = (iv - 17) >> 4;
            const int ok = (pacc[r] == (float)iv) && (iv >= 17) && (iv <= 272)
                           && (mm + 16 * nn + 17 == iv);
            okm &= ok;
            sum += iv - 17;
            rc[r] = mm | (nn << 8);
        }
        #pragma unroll
        for (int m = 1; m < 64; m <<= 1) {
            sum += __shfl_xor(sum, m);
            okm &= __shfl_xor(okm, m);
        }
        ((int4*)rctab)[lane] = make_int4(rc[0], rc[1], rc[2], rc[3]);
        // coverage: sum of (m+16n) over the 256 cells must be 32640
        if (lane == 0) *mapflag = (okm != 0 && sum == 32640) ? 1 : 0;
    }

    const int stride = gridDim.x * blockDim.x;
    for (int i = blockIdx.x * blockDim.x + threadIdx.x; i < n4; i += stride) {
        float4 f = ((const float4*)emb)[i];
        int q0 = (int)rintf(fminf(fmaxf(f.x * Q8SCALE, -127.f), 127.f));
        int q1 = (int)rintf(fminf(fmaxf(f.y * Q8SCALE, -127.f), 127.f));
        int q2 = (int)rintf(fminf(fmaxf(f.z * Q8SCALE, -127.f), 127.f));
        int q3 = (int)rintf(fminf(fmaxf(f.w * Q8SCALE, -127.f), 127.f));
        ((char4*)d8)[i] = make_char4((signed char)q0, (signed char)q1,
                                     (signed char)q2, (signed char)q3);
        int p0 = (int)rintf(fminf(fmaxf(f.x * Q4SCALE, -7.f), 7.f));
        int p1 = (int)rintf(fminf(fmaxf(f.y * Q4SCALE, -7.f), 7.f));
        int p2 = (int)rintf(fminf(fmaxf(f.z * Q4SCALE, -7.f), 7.f));
        int p3 = (int)rintf(fminf(fmaxf(f.w * Q4SCALE, -7.f), 7.f));
        unsigned char b0 = (unsigned char)((p0 & 0xF) | ((p1 & 0xF) << 4));
        unsigned char b1 = (unsigned char)((p2 & 0xF) | ((p3 & 0xF) << 4));
        ((uchar2*)d4)[i] = make_uchar2(b0, b1);
        if (i < nrel4) {
            int4 r = ((const int4*)adj_rel)[i];
            ((uchar4*)r8)[i] = make_uchar4((unsigned char)r.x, (unsigned char)r.y,
                                           (unsigned char)r.z, (unsigned char)r.w);
        }
        if (i < nw4) {
            float4 w = ((const float4*)W0)[i];
            ((ushort4*)w0b)[i] = make_ushort4(f2bf(w.x), f2bf(w.y),
                                              f2bf(w.z), f2bf(w.w));
        }
    }
}

// R17: R2(=R15)-proven body + Layer-0 on the matrix pipe, made layout-proof:
// h values are scattered to LDS through the probe's (row,col) table, so no
// fragment-layout assumption survives in the epilogue. Runtime fallback to
// the bit-identical R2 scalar path if the probe invalidates (mapflag==0).
template <bool Q8>
__global__ __launch_bounds__(64, 4) void kgnnls_kernel(
    const int* __restrict__ u_ids, const int* __restrict__ i_ids,
    const int* __restrict__ adj_entity, const int* __restrict__ adj_relation,
    const float* __restrict__ user_emb, const float* __restrict__ entity_emb,
    const signed char* __restrict__ et8,
    const unsigned char* __restrict__ et4,
    const unsigned char* __restrict__ rel8,
    const unsigned short* __restrict__ w0b,
    const int* __restrict__ rctab,
    const int* __restrict__ mapflag,
    const float* __restrict__ relation_emb,
    const float* __restrict__ W0, const float* __restrict__ b0,
    const float* __restrict__ W1, const float* __restrict__ b1,
    float* __restrict__ out, int B)
{
    const int lane = threadIdx.x;       // dual role: dim index d / output index e
    const int b = blockIdx.x;           // grid == B exactly

    __shared__ unsigned short xbf[32][72];                 // bf16 X (rows 0..16 used)
    __shared__ union { float x32[17][DIM]; float hb[17][68]; } us;
    __shared__ float uebuf[DIM];
    __shared__ float xLbuf[DIM];
    __shared__ float b0buf[DIM];

    bool usemfma = false;
    if (Q8) usemfma = (*mapflag != 0);   // wave-uniform scalar load

    const int u  = u_ids[b];
    const int i0 = i_ids[b];

    const float ue = user_emb[u * DIM + lane];
    uebuf[lane] = ue;
    b0buf[lane] = b0[lane];
    const float bias0 = b0[lane];
    __syncthreads();

    // s[r] at lane r (r < 33): s = (1/64) * dot(ue, relation_emb[r])  [R2 exact]
    float s_val = 0.f;
    if (lane < NREL + 1) {
        const float4* rrow = (const float4*)(relation_emb + lane * DIM);
        const float4* ub   = (const float4*)uebuf;
        float acc = 0.f;
        #pragma unroll
        for (int q = 0; q < 16; ++q) {
            float4 r4 = rrow[q];
            float4 u4 = ub[q];   // same address across lanes -> LDS broadcast
            acc += r4.x*u4.x + r4.y*u4.y + r4.z*u4.z + r4.w*u4.w;
        }
        s_val = acc * (1.0f / DIM);
    }

    // hop-0 neighbor/relation indices at lanes 0..15
    int e1k = 0, r0k = 0;
    if (lane < KNBR) {
        e1k = adj_entity[i0 * KNBR + lane];
        r0k = Q8 ? (int)rel8[i0 * KNBR + lane]
                 : adj_relation[i0 * KNBR + lane];
    }

    // softmax over k (16) for hop-0 scores, valid at lanes 0..15
    float sc0 = __shfl(s_val, r0k);
    float m0 = sc0;
    m0 = fmaxf(m0, __shfl_xor(m0, 1));
    m0 = fmaxf(m0, __shfl_xor(m0, 2));
    m0 = fmaxf(m0, __shfl_xor(m0, 4));
    m0 = fmaxf(m0, __shfl_xor(m0, 8));
    float ex0 = __expf(sc0 - m0);
    float z0 = ex0;
    z0 += __shfl_xor(z0, 1);
    z0 += __shfl_xor(z0, 2);
    z0 += __shfl_xor(z0, 4);
    z0 += __shfl_xor(z0, 8);
    const float attn0 = ex0 / z0;     // lanes 0..15 hold attn0[k]

    // hop-1: lane handles k = lane>>2, j in [4*(lane&3), +4)
    const int kk = lane >> 2;
    const int jb = (lane & 3) * 4;
    const int ek = __shfl(e1k, kk);
    const int4 e2i = *(const int4*)(adj_entity + ek * KNBR + jb);
    int e2idx[4] = { e2i.x, e2i.y, e2i.z, e2i.w };

    int r2x, r2y, r2z, r2w;
    if (Q8) {
        uchar4 rr = *(const uchar4*)(rel8 + ek * KNBR + jb);
        r2x = rr.x; r2y = rr.y; r2z = rr.z; r2w = rr.w;
    } else {
        const int4 r2i = *(const int4*)(adj_relation + ek * KNBR + jb);
        r2x = r2i.x; r2y = r2i.y; r2z = r2i.z; r2w = r2i.w;
    }

    float sc1[4];
    sc1[0] = __shfl(s_val, r2x);
    sc1[1] = __shfl(s_val, r2y);
    sc1[2] = __shfl(s_val, r2z);
    sc1[3] = __shfl(s_val, r2w);

    float m1 = fmaxf(fmaxf(sc1[0], sc1[1]), fmaxf(sc1[2], sc1[3]));
    m1 = fmaxf(m1, __shfl_xor(m1, 1));
    m1 = fmaxf(m1, __shfl_xor(m1, 2));
    float a1[4];
    float z1 = 0.f;
    #pragma unroll
    for (int t = 0; t < 4; ++t) { a1[t] = __expf(sc1[t] - m1); z1 += a1[t]; }
    z1 += __shfl_xor(z1, 1);
    z1 += __shfl_xor(z1, 2);
    const float inv_z1 = 1.0f / z1;
    #pragma unroll
    for (int t = 0; t < 4; ++t) a1[t] *= inv_z1;

    // ---- Gather phase (R2 exact, plus bf16 mirror of x into xbf) ----
    int v1raw[KNBR];
    #pragma unroll
    for (int k = 0; k < KNBR; ++k) {
        const int ei = irl(e1k, k);
        v1raw[k] = Q8 ? (int)et8[(size_t)ei * DIM + lane]
                      : __float_as_int(entity_emb[(size_t)ei * DIM + lane]);
    }
    const int ev0raw = Q8 ? (int)et8[(size_t)i0 * DIM + lane]
                          : __float_as_int(entity_emb[(size_t)i0 * DIM + lane]);

    const int sh = 28 - ((lane & 1) << 2);   // even lane: <<28; odd: <<24
    auto issue = [&](int* v2, int k) {
        #pragma unroll
        for (int j = 0; j < 16; ++j) {
            const int src = 4 * k + (j >> 2);
            const int ei2 = irl(e2idx[j & 3], src);
            v2[j] = Q8 ? (int)et4[(size_t)ei2 * 32 + (lane >> 1)]
                       : __float_as_int(entity_emb[(size_t)ei2 * DIM + lane]);
        }
    };
    auto consume = [&](const int* v2, int k) -> float {
        float acc = 0.f;
        #pragma unroll
        for (int j = 0; j < 16; ++j) {
            const float w = frl(a1[j & 3], 4 * k + (j >> 2));
            float v;
            if (Q8) {
                const int t = ((int)((unsigned)v2[j] << sh)) >> 28;
                v = (float)t;
            } else {
                v = __int_as_float(v2[j]);
            }
            acc += w * v;
        }
        return acc;
    };
    const float xsc = Q8 ? (1.0f / (KNBR * Q4SCALE)) : (1.0f / KNBR);
    const float vsc = Q8 ? (1.0f / Q8SCALE) : 1.0f;

    float agg0 = 0.f;
    int v2a[16], v2b[16];
    issue(v2a, 0);
    #pragma unroll
    for (int k = 0; k < KNBR; k += 2) {
        issue(v2b, k + 1);
        const float acca = consume(v2a, k);
        if (k + 2 < KNBR) issue(v2a, k + 2);
        const float accb = consume(v2b, k + 1);
        const float v1k0 = (Q8 ? (float)v1raw[k]     : __int_as_float(v1raw[k]))     * vsc;
        const float v1k1 = (Q8 ? (float)v1raw[k + 1] : __int_as_float(v1raw[k + 1])) * vsc;
        agg0 += frl(attn0, k) * v1k0 + frl(attn0, k + 1) * v1k1;
        const float x0 = v1k0 + acca * xsc;
        const float x1 = v1k1 + accb * xsc;
        us.x32[1 + k][lane] = x0;
        us.x32[2 + k][lane] = x1;
        xbf[1 + k][lane] = f2bf(x0);
        xbf[2 + k][lane] = f2bf(x1);
    }
    const float ev0 = (Q8 ? (float)ev0raw : __int_as_float(ev0raw)) * vsc;
    const float xself = ev0 + agg0 * (1.0f / KNBR);
    us.x32[0][lane] = xself;
    xbf[0][lane] = f2bf(xself);
    __syncthreads();

    float xL;
    if (Q8 && usemfma) {
        // ---- Layer-0 on the matrix pipe, table-attributed epilogue ----
        const int g = lane >> 4, c15 = lane & 15;
        short8 bfr[2][4];   // [kchunk][ntile]: W0 row 16t+c15, dims 32s+8g..+8
        #pragma unroll
        for (int s = 0; s < 2; ++s)
            #pragma unroll
            for (int t = 0; t < 4; ++t)
                bfr[s][t] = *(const short8*)(w0b + (16*t + c15) * DIM + 32*s + 8*g);

        floatx4 acc[2][4];
        #pragma unroll
        for (int mt = 0; mt < 2; ++mt)
            #pragma unroll
            for (int t = 0; t < 4; ++t)
                acc[mt][t] = (floatx4){0.f, 0.f, 0.f, 0.f};

        #pragma unroll
        for (int s = 0; s < 2; ++s) {
            short8 afr[2];
            #pragma unroll
            for (int mt = 0; mt < 2; ++mt)
                afr[mt] = *(const short8*)&xbf[16*mt + c15][32*s + 8*g];
            #pragma unroll
            for (int mt = 0; mt < 2; ++mt)
                #pragma unroll
                for (int t = 0; t < 4; ++t)
                    acc[mt][t] = __builtin_amdgcn_mfma_f32_16x16x32_bf16(
                        afr[mt], bfr[s][t], acc[mt][t], 0, 0, 0);
        }

        // probe table: true (row,col) of each (lane,reg) within a 16x16 tile
        const int4 rc4 = ((const int4*)rctab)[lane];
        const int mr[4] = { rc4.x & 255, rc4.y & 255, rc4.z & 255, rc4.w & 255 };
        const int nr[4] = { rc4.x >> 8,  rc4.y >> 8,  rc4.z >> 8,  rc4.w >> 8 };

        // scatter h = relu(acc + b0[col]) into hb[row][col] (overwrites x32 union)
        #pragma unroll
        for (int t = 0; t < 4; ++t) {
            #pragma unroll
            for (int r = 0; r < 4; ++r) {
                const int col = 16*t + nr[r];
                us.hb[mr[r]][col] = fmaxf(acc[0][t][r] + b0buf[col], 0.f);
            }
            #pragma unroll
            for (int r = 0; r < 4; ++r) {
                if (mr[r] == 0) {   // mt=1 tile rows are 16+mr -> keep row 16 only
                    const int col = 16*t + nr[r];
                    us.hb[16][col] = fmaxf(acc[1][t][r] + b0buf[col], 0.f);
                }
            }
        }
        __syncthreads();

        float aggL = 0.f;
        #pragma unroll
        for (int k = 0; k < KNBR; ++k)
            aggL += frl(attn0, k) * us.hb[1 + k][lane];
        xL = us.hb[0][lane] + aggL * (1.0f / KNBR);
    } else {
        // ---- Scalar Layer-0 (R2 exact) ----
        float h[17];
        #pragma unroll
        for (int r = 0; r < 17; ++r) h[r] = bias0;
        const float4* wrow = (const float4*)(W0 + lane * DIM);
        #pragma unroll
        for (int q = 0; q < 16; ++q) {
            float4 w = wrow[q];
            #pragma unroll
            for (int r = 0; r < 17; ++r) {
                float4 xv = ((const float4*)us.x32[r])[q];
                h[r] += xv.x * w.x + xv.y * w.y + xv.z * w.z + xv.w * w.w;
            }
        }
        #pragma unroll
        for (int r = 0; r < 17; ++r) h[r] = fmaxf(h[r], 0.f);
        float aggLs = 0.f;
        #pragma unroll
        for (int k = 0; k < KNBR; ++k)
            aggLs += frl(attn0, k) * h[1 + k];
        xL = h[0] + aggLs * (1.0f / KNBR);
    }
    __syncthreads();
    xLbuf[lane] = xL;
    __syncthreads();

    // Layer-1: tanh(xL @ W1^T + b1)   [R2 exact]
    float acc1 = b1[lane];
    {
        const float4* wrow = (const float4*)(W1 + lane * DIM);
        const float4* xb   = (const float4*)xLbuf;
        #pragma unroll
        for (int q = 0; q < 16; ++q) {
            float4 w  = wrow[q];
            float4 xv = xb[q];
            acc1 += xv.x * w.x + xv.y * w.y + xv.z * w.z + xv.w * w.w;
        }
    }
    const float item = tanhf(acc1);

    float p = ue * item;
    #pragma unroll
    for (int m = 1; m < 64; m <<= 1) p += __shfl_xor(p, m);
    if (lane == 0) out[b] = 1.0f / (1.0f + __expf(-p));
}

extern "C" void kernel_launch(void* const* d_in, const int* in_sizes, int n_in,
                              void* d_out, int out_size, void* d_ws, size_t ws_size,
                              hipStream_t stream) {
    const int*   u_ids        = (const int*)  d_in[0];
    const int*   i_ids        = (const int*)  d_in[1];
    const int*   adj_entity   = (const int*)  d_in[2];
    const int*   adj_relation = (const int*)  d_in[3];
    const float* user_emb     = (const float*)d_in[4];
    const float* entity_emb   = (const float*)d_in[5];
    const float* relation_emb = (const float*)d_in[6];
    const float* W0           = (const float*)d_in[7];
    const float* b0           = (const float*)d_in[8];
    const float* W1           = (const float*)d_in[9];
    const float* b1           = (const float*)d_in[10];
    float* out = (float*)d_out;

    const int B      = in_sizes[0];
    const int n_emb  = in_sizes[5];                 // N_ENTITIES * DIM (6.4M)
    const int n_rel  = in_sizes[3];                 // N_ENTITIES * K   (1.6M)
    const int n_w0   = in_sizes[7];                 // DIM * DIM (4096)
    // ws: [int8 n_emb][int4 n_emb/2][rel8 n_rel][w0bf 2*n_w0][rctab 1KB][flag]
    const size_t off4 = (size_t)n_emb;
    const size_t offr = off4 + (size_t)n_emb / 2;
    const size_t offw = offr + (size_t)n_rel;        // 16B-aligned (11.2e6)
    const size_t offp = offw + (size_t)n_w0 * 2;     // 16B-aligned
    const size_t ws_needed = offp + 2048;

    if (ws_size >= ws_needed) {
        signed char*    et8  = (signed char*)d_ws;
        unsigned char*  et4  = (unsigned char*)d_ws + off4;
        unsigned char*  rel8 = (unsigned char*)d_ws + offr;
        unsigned short* w0b  = (unsigned short*)((unsigned char*)d_ws + offw);
        int*            rct  = (int*)((unsigned char*)d_ws + offp);
        int*            flg  = rct + 256;
        hipLaunchKernelGGL(convert_tabs, dim3(1024), dim3(256), 0, stream,
            entity_emb, adj_relation, W0, et8, et4, rel8, w0b, rct, flg,
            n_emb / 4, n_rel / 4, n_w0 / 4);
        hipLaunchKernelGGL((kgnnls_kernel<true>), dim3(B), dim3(64), 0, stream,
            u_ids, i_ids, adj_entity, adj_relation, user_emb, entity_emb,
            et8, et4, rel8, w0b, rct, flg, relation_emb, W0, b0, W1, b1, out, B);
    } else {
        hipLaunchKernelGGL((kgnnls_kernel<false>), dim3(B), dim3(64), 0, stream,
            u_ids, i_ids, adj_entity, adj_relation, user_emb, entity_emb,
            (const signed char*)entity_emb /*unused*/,
            (const unsigned char*)entity_emb /*unused*/,
            (const unsigned char*)adj_relation /*unused*/,
            (const unsigned short*)entity_emb /*unused*/,
            (const int*)adj_entity /*unused*/,
            (const int*)adj_entity /*unused*/,
            relation_emb, W0, b0, W1, b1, out, B);
    }
}